// Round 5
// baseline (470.523 us; speedup 1.0000x reference)
//
#include <hip/hip_runtime.h>
#include <math.h>

// ============================ CSR build ============================

__global__ void count_kernel(const int* __restrict__ dst, int* __restrict__ deg, int E) {
  int i = blockIdx.x * 256 + threadIdx.x;
  if (i < E) atomicAdd(&deg[dst[i]], 1);
}

// exclusive scan of (deg[i]+1) (+1 = self loop); single block, 8 vals/thread
__global__ void scan_kernel(const int* __restrict__ deg, int* __restrict__ rowptr, int n) {
  __shared__ int buf[1024];
  __shared__ int carry;
  if (threadIdx.x == 0) carry = 0;
  __syncthreads();
  for (int base = 0; base < n; base += 8192) {
    int v[8];
    int tsum = 0;
    int i0 = base + (int)threadIdx.x * 8;
#pragma unroll
    for (int k = 0; k < 8; ++k) {
      int i = i0 + k;
      v[k] = (i < n) ? (deg[i] + 1) : 0;
      tsum += v[k];
    }
    int incl = tsum;
    buf[threadIdx.x] = incl;
    __syncthreads();
    for (int s = 1; s < 1024; s <<= 1) {
      int t = (threadIdx.x >= (unsigned)s) ? buf[threadIdx.x - s] : 0;
      __syncthreads();
      incl += t;
      buf[threadIdx.x] = incl;
      __syncthreads();
    }
    int excl = carry + incl - tsum;
#pragma unroll
    for (int k = 0; k < 8; ++k) {
      int i = i0 + k;
      if (i < n) rowptr[i] = excl;
      excl += v[k];
    }
    int total = buf[1023];
    __syncthreads();
    if (threadIdx.x == 0) carry += total;
    __syncthreads();
  }
  if (threadIdx.x == 0) rowptr[n] = carry;
}

__global__ void scatter_kernel(const int* __restrict__ src, const int* __restrict__ dst,
                               const int* __restrict__ rowptr, int* __restrict__ wp,
                               int* __restrict__ col, int E, int n) {
  int i = blockIdx.x * 256 + threadIdx.x;
  if (i < E) {
    int d = dst[i];
    int p = rowptr[d] + atomicAdd(&wp[d], 1);
    col[p] = src[i];
  } else if (i < E + n) {
    int d = i - E;
    int p = rowptr[d] + atomicAdd(&wp[d], 1);
    col[p] = d;
  }
}

// ============================ fp32 GEMM (projections) ============================
// C[M,*] = A[M,K] @ B[K,*] (+bias). blockIdx.z adds aZ/bZ/cZ/biasZ element
// offsets (per-head batched projections). BN=64, BK=16, 256 threads,
// per-thread (BMt/16)x4 accumulator.

template <int BMt>
__global__ __launch_bounds__(256) void gemm_kernel(
    const float* __restrict__ A, const float* __restrict__ B,
    float* __restrict__ C, const float* __restrict__ bias,
    int M, int K, int lda, int ldb, int ldc,
    int aZ, int bZ, int cZ, int biasZ) {
  constexpr int BNt = 64, BKt = 16;
  constexpr int TM = BMt / 16;  // rows per thread (8 or 4)
  __shared__ float As[BKt][BMt + 4];
  __shared__ float Bs[BKt][BNt];
  const int z = blockIdx.z;
  A += (size_t)z * aZ;
  B += (size_t)z * bZ;
  C += (size_t)z * cZ;
  const int tid = threadIdx.x;
  const int bm = blockIdx.y * BMt;
  const int bn = blockIdx.x * BNt;
  const int tm = (tid >> 4) * TM;
  const int tn = (tid & 15) * 4;
  float acc[TM][4] = {};
  for (int k0 = 0; k0 < K; k0 += BKt) {
#pragma unroll
    for (int i = 0; i < BMt * BKt / 1024; ++i) {
      int idx = tid + i * 256;
      int row = idx >> 2;
      int kq = (idx & 3) * 4;
      float4 av = make_float4(0.f, 0.f, 0.f, 0.f);
      if (bm + row < M)
        av = *reinterpret_cast<const float4*>(A + (size_t)(bm + row) * lda + k0 + kq);
      As[kq + 0][row] = av.x; As[kq + 1][row] = av.y;
      As[kq + 2][row] = av.z; As[kq + 3][row] = av.w;
    }
    {
      int bk = tid >> 4, bn4 = (tid & 15) * 4;
      *reinterpret_cast<float4*>(&Bs[bk][bn4]) =
          *reinterpret_cast<const float4*>(B + (size_t)(k0 + bk) * ldb + bn + bn4);
    }
    __syncthreads();
#pragma unroll
    for (int k = 0; k < BKt; ++k) {
      float a[TM], b[4];
#pragma unroll
      for (int i = 0; i < TM; ++i) a[i] = As[k][tm + i];
#pragma unroll
      for (int j = 0; j < 4; ++j) b[j] = Bs[k][tn + j];
#pragma unroll
      for (int i = 0; i < TM; ++i)
#pragma unroll
        for (int j = 0; j < 4; ++j) acc[i][j] = fmaf(a[i], b[j], acc[i][j]);
    }
    __syncthreads();
  }
  float4 bz = make_float4(0.f, 0.f, 0.f, 0.f);
  if (bias) bz = *reinterpret_cast<const float4*>(bias + (size_t)z * biasZ + bn + tn);
#pragma unroll
  for (int i = 0; i < TM; ++i) {
    int m = bm + tm + i;
    if (m < M) {
      float4 o;
      o.x = acc[i][0] + bz.x; o.y = acc[i][1] + bz.y;
      o.z = acc[i][2] + bz.z; o.w = acc[i][3] + bz.w;
      *reinterpret_cast<float4*>(C + (size_t)m * ldc + bn + tn) = o;
    }
  }
}

// ==================== fused LSTM GEMM + activation + attcoef2 ====================
// gates = g1[M,512] @ Wt[512,192] + bsum; h2 = relu(sigmoid(o)*tanh(sigmoid(i)*tanh(g)))
// computed in registers (thread tile 4 rows x {i,g,o}xfloat4 cols); h2 tile then
// round-trips LDS (union'd with staging bufs) to emit a_s2/a_d2 per block.

__global__ __launch_bounds__(256) void lstm_fused_kernel(
    const float* __restrict__ A, const float* __restrict__ Bt,
    const float* __restrict__ bsum, const float* __restrict__ watt2,
    float* __restrict__ h2, float* __restrict__ a_s2, float* __restrict__ a_d2,
    int M) {
  constexpr int BK = 16;
  __shared__ union {
    struct { float As[BK][68]; float Bs[BK][192]; } s;   // 16640 B
    struct { float h2t[64][65]; } e;                     // 16900 B
  } u;
  __shared__ float wbuf[64 * 16];
  const int tid = threadIdx.x;
  const int bm = blockIdx.x * 64;
  for (int i = tid; i < 64 * 16 / 4; i += 256)
    reinterpret_cast<float4*>(wbuf)[i] = reinterpret_cast<const float4*>(watt2)[i];
  const int tm = (tid >> 4) * 4;   // 4 rows per thread
  const int c = (tid & 15) * 4;    // col base within each gate block
  float acc[4][12] = {};
  for (int k0 = 0; k0 < 512; k0 += BK) {
    {  // stage A: 64x16, one float4 per thread
      int row = tid >> 2, kq = (tid & 3) * 4;
      float4 av = make_float4(0.f, 0.f, 0.f, 0.f);
      if (bm + row < M)
        av = *reinterpret_cast<const float4*>(A + (size_t)(bm + row) * 512 + k0 + kq);
      u.s.As[kq + 0][row] = av.x; u.s.As[kq + 1][row] = av.y;
      u.s.As[kq + 2][row] = av.z; u.s.As[kq + 3][row] = av.w;
    }
#pragma unroll
    for (int i = 0; i < 3; ++i) {  // stage B: 16x192 = 768 float4s
      int idx = tid + i * 256;
      int bk = idx / 48;
      int bn4 = (idx - bk * 48) * 4;
      *reinterpret_cast<float4*>(&u.s.Bs[bk][bn4]) =
          *reinterpret_cast<const float4*>(Bt + (size_t)(k0 + bk) * 192 + bn4);
    }
    __syncthreads();
#pragma unroll
    for (int k = 0; k < BK; ++k) {
      float4 av = *reinterpret_cast<const float4*>(&u.s.As[k][tm]);
      float4 bi = *reinterpret_cast<const float4*>(&u.s.Bs[k][c]);
      float4 bg = *reinterpret_cast<const float4*>(&u.s.Bs[k][64 + c]);
      float4 bo = *reinterpret_cast<const float4*>(&u.s.Bs[k][128 + c]);
      float ar[4] = {av.x, av.y, av.z, av.w};
#pragma unroll
      for (int i = 0; i < 4; ++i) {
        acc[i][0] = fmaf(ar[i], bi.x, acc[i][0]);
        acc[i][1] = fmaf(ar[i], bi.y, acc[i][1]);
        acc[i][2] = fmaf(ar[i], bi.z, acc[i][2]);
        acc[i][3] = fmaf(ar[i], bi.w, acc[i][3]);
        acc[i][4] = fmaf(ar[i], bg.x, acc[i][4]);
        acc[i][5] = fmaf(ar[i], bg.y, acc[i][5]);
        acc[i][6] = fmaf(ar[i], bg.z, acc[i][6]);
        acc[i][7] = fmaf(ar[i], bg.w, acc[i][7]);
        acc[i][8] = fmaf(ar[i], bo.x, acc[i][8]);
        acc[i][9] = fmaf(ar[i], bo.y, acc[i][9]);
        acc[i][10] = fmaf(ar[i], bo.z, acc[i][10]);
        acc[i][11] = fmaf(ar[i], bo.w, acc[i][11]);
      }
    }
    __syncthreads();
  }
  // epilogue: bias + LSTM activation + relu, in registers
  float4 zi = *reinterpret_cast<const float4*>(bsum + c);
  float4 zg = *reinterpret_cast<const float4*>(bsum + 64 + c);
  float4 zo = *reinterpret_cast<const float4*>(bsum + 128 + c);
  float bi4[4] = {zi.x, zi.y, zi.z, zi.w};
  float bg4[4] = {zg.x, zg.y, zg.z, zg.w};
  float bo4[4] = {zo.x, zo.y, zo.z, zo.w};
#pragma unroll
  for (int i = 0; i < 4; ++i) {
    float hv[4];
#pragma unroll
    for (int jj = 0; jj < 4; ++jj) {
      float iv = acc[i][jj] + bi4[jj];
      float gv = acc[i][4 + jj] + bg4[jj];
      float ov = acc[i][8 + jj] + bo4[jj];
      float cs = (1.f / (1.f + __expf(-iv))) * tanhf(gv);
      float hh = (1.f / (1.f + __expf(-ov))) * tanhf(cs);
      hv[jj] = fmaxf(hh, 0.f);
    }
    int m = bm + tm + i;
    float4 o = make_float4(hv[0], hv[1], hv[2], hv[3]);
    u.e.h2t[tm + i][c] = hv[0]; u.e.h2t[tm + i][c + 1] = hv[1];
    u.e.h2t[tm + i][c + 2] = hv[2]; u.e.h2t[tm + i][c + 3] = hv[3];
    if (m < M) *reinterpret_cast<float4*>(h2 + (size_t)m * 64 + c) = o;
  }
  __syncthreads();
  // attcoef2: 64 rows x 16 coefs; thread -> (row = tid>>2, coefs (tid&3)*4..+3)
  const int r = tid >> 2;
  const int c4 = (tid & 3) * 4;
  if (bm + r < M) {
    float s0 = 0.f, s1 = 0.f, s2 = 0.f, s3 = 0.f;
#pragma unroll 16
    for (int f = 0; f < 64; ++f) {
      float hvv = u.e.h2t[r][f];
      s0 = fmaf(hvv, wbuf[f * 16 + c4 + 0], s0);
      s1 = fmaf(hvv, wbuf[f * 16 + c4 + 1], s1);
      s2 = fmaf(hvv, wbuf[f * 16 + c4 + 2], s2);
      s3 = fmaf(hvv, wbuf[f * 16 + c4 + 3], s3);
    }
    float sv[4] = {s0, s1, s2, s3};
#pragma unroll
    for (int cc = 0; cc < 4; ++cc) {
      int idx = c4 + cc;
      if (idx < 8) a_s2[(size_t)(bm + r) * 8 + idx] = sv[cc];
      else         a_d2[(size_t)(bm + r) * 8 + (idx - 8)] = sv[cc];
    }
  }
}

// ==================== attention weight-vector prep ====================
// watt[f][c] = sum_j W[f, k*64+j] * att[k][j], c<8: att_src (k=c), c>=8: att_dst

__global__ void prep_watt_kernel(const float* __restrict__ W, const float* __restrict__ att_s,
                                 const float* __restrict__ att_d, float* __restrict__ watt,
                                 int F) {
  int idx = blockIdx.x * 256 + threadIdx.x;
  if (idx >= F * 16) return;
  int f = idx >> 4, c = idx & 15;
  int k = c & 7;
  const float* att = ((c < 8) ? att_s : att_d) + k * 64;
  const float* w = W + (size_t)f * 512 + k * 64;
  float s = 0.f;
#pragma unroll
  for (int j = 0; j < 64; ++j) s = fmaf(w[j], att[j], s);
  watt[idx] = s;
}

// ==================== attention coefficients (layer 1) ====================

template <int F>
__global__ __launch_bounds__(256) void attcoef_kernel(
    const float* __restrict__ feat, const float* __restrict__ watt,
    float* __restrict__ a_s, float* __restrict__ a_d, int n) {
  __shared__ float rows[16 * F];
  __shared__ float wbuf[F * 16];
  const int n0 = blockIdx.x * 16;
  const int tid = threadIdx.x;
  if (n0 + 16 <= n) {
    const float4* g = reinterpret_cast<const float4*>(feat + (size_t)n0 * F);
    float4* l = reinterpret_cast<float4*>(rows);
    for (int i = tid; i < 16 * F / 4; i += 256) l[i] = g[i];
  } else {
    for (int i = tid; i < 16 * F; i += 256) {
      int r = i / F;
      rows[i] = (n0 + r < n) ? feat[(size_t)(n0 + r) * F + (i - r * F)] : 0.f;
    }
  }
  {
    const float4* g = reinterpret_cast<const float4*>(watt);
    float4* l = reinterpret_cast<float4*>(wbuf);
    for (int i = tid; i < F * 16 / 4; i += 256) l[i] = g[i];
  }
  __syncthreads();
  const int local = tid >> 4, c = tid & 15;
  float s = 0.f;
#pragma unroll 8
  for (int f = 0; f < F; ++f) s = fmaf(rows[local * F + f], wbuf[f * 16 + c], s);
  const int node = n0 + local;
  if (node < n) {
    if (c < 8) a_s[(size_t)node * 8 + c] = s;
    else       a_d[(size_t)node * 8 + (c - 8)] = s;
  }
}

// ==================== GAT pre-aggregation: one WAVE per dst node ====================
// 4 independent waves/block, no __syncthreads. Heads split across lane GROUPS;
// explicit float4 accumulators (no indexed local arrays -> no scratch spill).
// Alpha + col staged in per-wave LDS chunks of 8 edges (DS ops wave-ordered).
// No max-subtraction: |a_s+a_d| <~ 8 so exp is safe.

template <int F>
__global__ __launch_bounds__(256) void gat_aggregate_wave(
    const float* __restrict__ feat, const float* __restrict__ a_s,
    const float* __restrict__ a_d, const int* __restrict__ rowptr,
    const int* __restrict__ col, float* __restrict__ agg, int n) {
  constexpr int F4 = F / 4;
  constexpr int HPG = (F == 128) ? 4 : 2;
  __shared__ float s_alpha[4][8][8];
  __shared__ int s_cols[4][8];
  const int wid = threadIdx.x >> 6;
  const int lane = threadIdx.x & 63;
  const int node = blockIdx.x * 4 + wid;
  if (node >= n) return;
  const int start = rowptr[node];
  const int deg = rowptr[node + 1] - start;
  const int j = lane >> 3;
  const int h = lane & 7;
  const float adh = a_d[(size_t)node * 8 + h];
  float den = 0.f;
  for (int e = j; e < deg; e += 8) {
    int s = col[start + e];
    float v = a_s[(size_t)s * 8 + h] + adh;
    v = (v > 0.f) ? v : 0.2f * v;
    den += __expf(v);
  }
  den += __shfl_xor(den, 8);
  den += __shfl_xor(den, 16);
  den += __shfl_xor(den, 32);
  const float inv = 1.f / (den + 1e-16f);
  const int f4 = lane & (F4 - 1);
  const int hbase = (lane / F4) * HPG;
  float4 acc0 = make_float4(0.f, 0.f, 0.f, 0.f);
  float4 acc1 = make_float4(0.f, 0.f, 0.f, 0.f);
  float4 acc2 = make_float4(0.f, 0.f, 0.f, 0.f);
  float4 acc3 = make_float4(0.f, 0.f, 0.f, 0.f);
  for (int c0 = 0; c0 < deg; c0 += 8) {
    float aval = 0.f;
    int sj = 0;
    if (c0 + j < deg) {
      sj = col[start + c0 + j];
      float v = a_s[(size_t)sj * 8 + h] + adh;
      v = (v > 0.f) ? v : 0.2f * v;
      aval = __expf(v) * inv;
    }
    s_alpha[wid][j][h] = aval;
    if (h == 0) s_cols[wid][j] = sj;
    __builtin_amdgcn_wave_barrier();
    const int ce = min(8, deg - c0);
    for (int e = 0; e < ce; ++e) {
      int s = s_cols[wid][e];
      float4 fv = *reinterpret_cast<const float4*>(feat + (size_t)s * F + f4 * 4);
      if constexpr (HPG == 4) {
        float4 al = *reinterpret_cast<const float4*>(&s_alpha[wid][e][hbase]);
        acc0.x = fmaf(al.x, fv.x, acc0.x); acc0.y = fmaf(al.x, fv.y, acc0.y);
        acc0.z = fmaf(al.x, fv.z, acc0.z); acc0.w = fmaf(al.x, fv.w, acc0.w);
        acc1.x = fmaf(al.y, fv.x, acc1.x); acc1.y = fmaf(al.y, fv.y, acc1.y);
        acc1.z = fmaf(al.y, fv.z, acc1.z); acc1.w = fmaf(al.y, fv.w, acc1.w);
        acc2.x = fmaf(al.z, fv.x, acc2.x); acc2.y = fmaf(al.z, fv.y, acc2.y);
        acc2.z = fmaf(al.z, fv.z, acc2.z); acc2.w = fmaf(al.z, fv.w, acc2.w);
        acc3.x = fmaf(al.w, fv.x, acc3.x); acc3.y = fmaf(al.w, fv.y, acc3.y);
        acc3.z = fmaf(al.w, fv.z, acc3.z); acc3.w = fmaf(al.w, fv.w, acc3.w);
      } else {
        float2 al = *reinterpret_cast<const float2*>(&s_alpha[wid][e][hbase]);
        acc0.x = fmaf(al.x, fv.x, acc0.x); acc0.y = fmaf(al.x, fv.y, acc0.y);
        acc0.z = fmaf(al.x, fv.z, acc0.z); acc0.w = fmaf(al.x, fv.w, acc0.w);
        acc1.x = fmaf(al.y, fv.x, acc1.x); acc1.y = fmaf(al.y, fv.y, acc1.y);
        acc1.z = fmaf(al.y, fv.z, acc1.z); acc1.w = fmaf(al.y, fv.w, acc1.w);
      }
    }
    __builtin_amdgcn_wave_barrier();
  }
  float* outp = agg + (size_t)node * 8 * F + (size_t)hbase * F + f4 * 4;
  *reinterpret_cast<float4*>(outp) = acc0;
  *reinterpret_cast<float4*>(outp + F) = acc1;
  if constexpr (HPG == 4) {
    *reinterpret_cast<float4*>(outp + 2 * F) = acc2;
    *reinterpret_cast<float4*>(outp + 3 * F) = acc3;
  }
}

// ==================== LSTM weight prep ====================
// Only i,g,o gates needed (f gate multiplies c0=0). Packed 192 columns.

__global__ void prep_lstm_kernel(const float* __restrict__ W_ih, const float* __restrict__ b_ih,
                                 const float* __restrict__ b_hh, float* __restrict__ Wt,
                                 float* __restrict__ bsum) {
  int idx = blockIdx.x * 256 + threadIdx.x;
  if (idx < 512 * 192) {
    int k = idx / 192, jp = idx - k * 192;
    int j = (jp < 64) ? jp : jp + 64;
    Wt[idx] = W_ih[(size_t)j * 512 + k];
  }
  if (idx < 192) {
    int j = (idx < 64) ? idx : idx + 64;
    bsum[idx] = b_ih[j] + b_hh[j];
  }
}

// ==================== final row softmax (512 wide) ====================

__global__ __launch_bounds__(256) void softmax512_kernel(const float* __restrict__ in,
                                                         float* __restrict__ out) {
  const int node = blockIdx.x;
  const int tid = threadIdx.x;
  __shared__ float red[256];
  float v0 = in[(size_t)node * 512 + tid];
  float v1 = in[(size_t)node * 512 + 256 + tid];
  red[tid] = fmaxf(v0, v1);
  __syncthreads();
  for (int s = 128; s >= 1; s >>= 1) {
    if (tid < s) red[tid] = fmaxf(red[tid], red[tid + s]);
    __syncthreads();
  }
  float mm = red[0];
  __syncthreads();
  float e0 = expf(v0 - mm), e1 = expf(v1 - mm);
  red[tid] = e0 + e1;
  __syncthreads();
  for (int s = 128; s >= 1; s >>= 1) {
    if (tid < s) red[tid] += red[tid + s];
    __syncthreads();
  }
  float inv = 1.f / red[0];
  out[(size_t)node * 512 + tid] = e0 * inv;
  out[(size_t)node * 512 + 256 + tid] = e1 * inv;
}

// ============================ launch ============================

extern "C" void kernel_launch(void* const* d_in, const int* in_sizes, int n_in,
                              void* d_out, int out_size, void* d_ws, size_t ws_size,
                              hipStream_t stream) {
  const float* x      = (const float*)d_in[0];
  const int*   ei     = (const int*)d_in[1];
  const float* W1     = (const float*)d_in[3];
  const float* att_s1 = (const float*)d_in[4];
  const float* att_d1 = (const float*)d_in[5];
  const float* bias1  = (const float*)d_in[6];
  const float* W_ih   = (const float*)d_in[7];
  const float* b_ih   = (const float*)d_in[9];
  const float* b_hh   = (const float*)d_in[10];
  const float* W2     = (const float*)d_in[11];
  const float* att_s2 = (const float*)d_in[12];
  const float* att_d2 = (const float*)d_in[13];
  const float* bias2  = (const float*)d_in[14];
  float* out = (float*)d_out;

  const int N = in_sizes[0] / 128;
  const int E = in_sizes[1] / 2;
  const int* src = ei;
  const int* dst = ei + E;

  char* p = (char*)d_ws;
  auto alloc = [&](size_t bytes) {
    char* r = p;
    p += (bytes + 255) & ~(size_t)255;
    return r;
  };
  float* slotA = (float*)alloc((size_t)N * 1024 * 4);  // agg1; later h2+agg2
  float* slotB = (float*)alloc((size_t)N * 512 * 4);   // g1; later h3p
  float* a_s1 = (float*)alloc((size_t)N * 8 * 4);
  float* a_d1 = (float*)alloc((size_t)N * 8 * 4);
  float* a_s2 = (float*)alloc((size_t)N * 8 * 4);
  float* a_d2 = (float*)alloc((size_t)N * 8 * 4);
  float* watt1 = (float*)alloc(128 * 16 * 4);
  float* watt2 = (float*)alloc(64 * 16 * 4);
  float* Wt   = (float*)alloc((size_t)512 * 192 * 4);
  float* bsum = (float*)alloc(192 * 4);
  int* deg    = (int*)alloc((size_t)2 * N * 4);  // deg + wp adjacent (one memset)
  int* wp     = deg + N;
  int* rowptr = (int*)alloc((size_t)(N + 1) * 4);
  int* col    = (int*)alloc((size_t)(E + N) * 4);

  float* agg1  = slotA;                   // [N,8,128], dead after proj1
  float* g1    = slotB;                   // [N,512], dead after fused LSTM
  float* h2    = slotA;                   // [N,64]
  float* agg2  = slotA + (size_t)N * 64;  // [N,8,64]
  float* h3p   = slotB;                   // [N,512] logits

  // ---- CSR build ----
  hipMemsetAsync(deg, 0, (size_t)2 * N * 4, stream);
  count_kernel<<<(E + 255) / 256, 256, 0, stream>>>(dst, deg, E);
  scan_kernel<<<1, 1024, 0, stream>>>(deg, rowptr, N);
  scatter_kernel<<<(E + N + 255) / 256, 256, 0, stream>>>(src, dst, rowptr, wp, col, E, N);

  // ---- weight prep ----
  prep_watt_kernel<<<(128 * 16 + 255) / 256, 256, 0, stream>>>(W1, att_s1, att_d1, watt1, 128);
  prep_watt_kernel<<<(64 * 16 + 255) / 256, 256, 0, stream>>>(W2, att_s2, att_d2, watt2, 64);
  prep_lstm_kernel<<<(512 * 192 + 255) / 256, 256, 0, stream>>>(W_ih, b_ih, b_hh, Wt, bsum);

  // ---- GATConv1: coeffs on x, aggregate x, project ----
  attcoef_kernel<128><<<(N + 15) / 16, 256, 0, stream>>>(x, watt1, a_s1, a_d1, N);
  gat_aggregate_wave<128><<<(N + 3) / 4, 256, 0, stream>>>(x, a_s1, a_d1, rowptr, col, agg1, N);
  {
    dim3 g(1, (N + 127) / 128, 8);
    gemm_kernel<128><<<g, 256, 0, stream>>>(agg1, W1, g1, bias1,
                                            N, 128, 1024, 512, 512, 128, 64, 64, 64);
  }

  // ---- fused LSTM GEMM + activation + attcoef2 ----
  lstm_fused_kernel<<<(N + 63) / 64, 256, 0, stream>>>(g1, Wt, bsum, watt2,
                                                       h2, a_s2, a_d2, N);

  // ---- GATConv2: aggregate h2, project, row softmax ----
  gat_aggregate_wave<64><<<(N + 3) / 4, 256, 0, stream>>>(h2, a_s2, a_d2, rowptr, col, agg2, N);
  {
    dim3 g(1, (N + 127) / 128, 8);
    gemm_kernel<128><<<g, 256, 0, stream>>>(agg2, W2, h3p, bias2,
                                            N, 64, 512, 512, 512, 64, 64, 64, 64);
  }
  softmax512_kernel<<<N, 256, 0, stream>>>(h3p, out);
}

// Round 6
// 414.686 us; speedup vs baseline: 1.1346x; 1.1346x over previous
//
#include <hip/hip_runtime.h>
#include <math.h>

// ============================ CSR build ============================

__global__ void count_kernel(const int* __restrict__ dst, int* __restrict__ deg, int E) {
  int i = blockIdx.x * 256 + threadIdx.x;
  if (i < E) atomicAdd(&deg[dst[i]], 1);
}

// exclusive scan of (deg[i]+1) (+1 = self loop); single block, 8 vals/thread
__global__ void scan_kernel(const int* __restrict__ deg, int* __restrict__ rowptr, int n) {
  __shared__ int buf[1024];
  __shared__ int carry;
  if (threadIdx.x == 0) carry = 0;
  __syncthreads();
  for (int base = 0; base < n; base += 8192) {
    int v[8];
    int tsum = 0;
    int i0 = base + (int)threadIdx.x * 8;
#pragma unroll
    for (int k = 0; k < 8; ++k) {
      int i = i0 + k;
      v[k] = (i < n) ? (deg[i] + 1) : 0;
      tsum += v[k];
    }
    int incl = tsum;
    buf[threadIdx.x] = incl;
    __syncthreads();
    for (int s = 1; s < 1024; s <<= 1) {
      int t = (threadIdx.x >= (unsigned)s) ? buf[threadIdx.x - s] : 0;
      __syncthreads();
      incl += t;
      buf[threadIdx.x] = incl;
      __syncthreads();
    }
    int excl = carry + incl - tsum;
#pragma unroll
    for (int k = 0; k < 8; ++k) {
      int i = i0 + k;
      if (i < n) rowptr[i] = excl;
      excl += v[k];
    }
    int total = buf[1023];
    __syncthreads();
    if (threadIdx.x == 0) carry += total;
    __syncthreads();
  }
  if (threadIdx.x == 0) rowptr[n] = carry;
}

__global__ void scatter_kernel(const int* __restrict__ src, const int* __restrict__ dst,
                               const int* __restrict__ rowptr, int* __restrict__ wp,
                               int* __restrict__ col, int E, int n) {
  int i = blockIdx.x * 256 + threadIdx.x;
  if (i < E) {
    int d = dst[i];
    int p = rowptr[d] + atomicAdd(&wp[d], 1);
    col[p] = src[i];
  } else if (i < E + n) {
    int d = i - E;
    int p = rowptr[d] + atomicAdd(&wp[d], 1);
    col[p] = d;
  }
}

// ============================ fp32 GEMM (register-prefetch) ============================
// C[M,*] = A[M,K] @ B[K,*] (+bias). blockIdx.z adds aZ/bZ/cZ/biasZ element
// offsets (per-head batched projections). BN=64, BK=16, 256 threads,
// per-thread (BMt/16)x4 accumulator. Next K-tile is loaded into registers
// BEFORE the FMA loop so the vmcnt drain overlaps ~512 FMA cycles (G7).

template <int BMt>
__global__ __launch_bounds__(256) void gemm_kernel(
    const float* __restrict__ A, const float* __restrict__ B,
    float* __restrict__ C, const float* __restrict__ bias,
    int M, int K, int lda, int ldb, int ldc,
    int aZ, int bZ, int cZ, int biasZ) {
  constexpr int BNt = 64, BKt = 16;
  constexpr int TM = BMt / 16;                  // rows per thread (8 or 4)
  constexpr int AST = (BMt * BKt) / (256 * 4);  // A float4 stages per thread (2 or 1)
  __shared__ float As[BKt][BMt + 4];
  __shared__ float Bs[BKt][BNt];
  const int z = blockIdx.z;
  A += (size_t)z * aZ;
  B += (size_t)z * bZ;
  C += (size_t)z * cZ;
  const int tid = threadIdx.x;
  const int bm = blockIdx.y * BMt;
  const int bn = blockIdx.x * BNt;
  const int tm = (tid >> 4) * TM;
  const int tn = (tid & 15) * 4;
  int arow_[AST], akq_[AST];
#pragma unroll
  for (int i = 0; i < AST; ++i) {
    int idx = tid + i * 256;
    arow_[i] = idx >> 2;
    akq_[i] = (idx & 3) * 4;
  }
  const int bk = tid >> 4, bn4 = (tid & 15) * 4;
  float4 pa[AST], pb;
#pragma unroll
  for (int i = 0; i < AST; ++i) {
    pa[i] = make_float4(0.f, 0.f, 0.f, 0.f);
    if (bm + arow_[i] < M)
      pa[i] = *reinterpret_cast<const float4*>(A + (size_t)(bm + arow_[i]) * lda + akq_[i]);
  }
  pb = *reinterpret_cast<const float4*>(B + (size_t)bk * ldb + bn + bn4);
  float acc[TM][4] = {};
  for (int k0 = 0; k0 < K; k0 += BKt) {
#pragma unroll
    for (int i = 0; i < AST; ++i) {
      As[akq_[i] + 0][arow_[i]] = pa[i].x; As[akq_[i] + 1][arow_[i]] = pa[i].y;
      As[akq_[i] + 2][arow_[i]] = pa[i].z; As[akq_[i] + 3][arow_[i]] = pa[i].w;
    }
    *reinterpret_cast<float4*>(&Bs[bk][bn4]) = pb;
    __syncthreads();
    const int kn = k0 + BKt;
    if (kn < K) {  // prefetch next tile into registers (overlaps FMA loop below)
#pragma unroll
      for (int i = 0; i < AST; ++i) {
        float4 t = make_float4(0.f, 0.f, 0.f, 0.f);
        if (bm + arow_[i] < M)
          t = *reinterpret_cast<const float4*>(A + (size_t)(bm + arow_[i]) * lda + kn + akq_[i]);
        pa[i] = t;
      }
      pb = *reinterpret_cast<const float4*>(B + (size_t)(kn + bk) * ldb + bn + bn4);
    }
#pragma unroll
    for (int k = 0; k < BKt; ++k) {
      float a[TM], b[4];
#pragma unroll
      for (int i = 0; i < TM; ++i) a[i] = As[k][tm + i];
#pragma unroll
      for (int j = 0; j < 4; ++j) b[j] = Bs[k][tn + j];
#pragma unroll
      for (int i = 0; i < TM; ++i)
#pragma unroll
        for (int j = 0; j < 4; ++j) acc[i][j] = fmaf(a[i], b[j], acc[i][j]);
    }
    __syncthreads();
  }
  float4 bz = make_float4(0.f, 0.f, 0.f, 0.f);
  if (bias) bz = *reinterpret_cast<const float4*>(bias + (size_t)z * biasZ + bn + tn);
#pragma unroll
  for (int i = 0; i < TM; ++i) {
    int m = bm + tm + i;
    if (m < M) {
      float4 o;
      o.x = acc[i][0] + bz.x; o.y = acc[i][1] + bz.y;
      o.z = acc[i][2] + bz.z; o.w = acc[i][3] + bz.w;
      *reinterpret_cast<float4*>(C + (size_t)m * ldc + bn + tn) = o;
    }
  }
}

// ==================== attention weight-vector prep ====================
// watt[f][c] = sum_j W[f, k*64+j] * att[k][j], c<8: att_src (k=c), c>=8: att_dst

__global__ void prep_watt_kernel(const float* __restrict__ W, const float* __restrict__ att_s,
                                 const float* __restrict__ att_d, float* __restrict__ watt,
                                 int F) {
  int idx = blockIdx.x * 256 + threadIdx.x;
  if (idx >= F * 16) return;
  int f = idx >> 4, c = idx & 15;
  int k = c & 7;
  const float* att = ((c < 8) ? att_s : att_d) + k * 64;
  const float* w = W + (size_t)f * 512 + k * 64;
  float s = 0.f;
#pragma unroll
  for (int j = 0; j < 64; ++j) s = fmaf(w[j], att[j], s);
  watt[idx] = s;
}

// ==================== attention coefficients (layer 1) ====================

template <int F>
__global__ __launch_bounds__(256) void attcoef_kernel(
    const float* __restrict__ feat, const float* __restrict__ watt,
    float* __restrict__ a_s, float* __restrict__ a_d, int n) {
  __shared__ float rows[16 * F];
  __shared__ float wbuf[F * 16];
  const int n0 = blockIdx.x * 16;
  const int tid = threadIdx.x;
  if (n0 + 16 <= n) {
    const float4* g = reinterpret_cast<const float4*>(feat + (size_t)n0 * F);
    float4* l = reinterpret_cast<float4*>(rows);
    for (int i = tid; i < 16 * F / 4; i += 256) l[i] = g[i];
  } else {
    for (int i = tid; i < 16 * F; i += 256) {
      int r = i / F;
      rows[i] = (n0 + r < n) ? feat[(size_t)(n0 + r) * F + (i - r * F)] : 0.f;
    }
  }
  {
    const float4* g = reinterpret_cast<const float4*>(watt);
    float4* l = reinterpret_cast<float4*>(wbuf);
    for (int i = tid; i < F * 16 / 4; i += 256) l[i] = g[i];
  }
  __syncthreads();
  const int local = tid >> 4, c = tid & 15;
  float s = 0.f;
#pragma unroll 8
  for (int f = 0; f < F; ++f) s = fmaf(rows[local * F + f], wbuf[f * 16 + c], s);
  const int node = n0 + local;
  if (node < n) {
    if (c < 8) a_s[(size_t)node * 8 + c] = s;
    else       a_d[(size_t)node * 8 + (c - 8)] = s;
  }
}

// ==================== GAT pre-aggregation: one WAVE per dst node ====================
// 4 independent waves/block, no __syncthreads. Heads split across lane GROUPS;
// explicit float4 accumulators (no indexed local arrays -> no scratch spill).
// Alpha + col staged in per-wave LDS chunks of 8 edges (DS ops wave-ordered).
// No max-subtraction: |a_s+a_d| <~ 8 so exp is safe.

template <int F>
__global__ __launch_bounds__(256) void gat_aggregate_wave(
    const float* __restrict__ feat, const float* __restrict__ a_s,
    const float* __restrict__ a_d, const int* __restrict__ rowptr,
    const int* __restrict__ col, float* __restrict__ agg, int n) {
  constexpr int F4 = F / 4;
  constexpr int HPG = (F == 128) ? 4 : 2;
  __shared__ float s_alpha[4][8][8];
  __shared__ int s_cols[4][8];
  const int wid = threadIdx.x >> 6;
  const int lane = threadIdx.x & 63;
  const int node = blockIdx.x * 4 + wid;
  if (node >= n) return;
  const int start = rowptr[node];
  const int deg = rowptr[node + 1] - start;
  const int j = lane >> 3;
  const int h = lane & 7;
  const float adh = a_d[(size_t)node * 8 + h];
  float den = 0.f;
  for (int e = j; e < deg; e += 8) {
    int s = col[start + e];
    float v = a_s[(size_t)s * 8 + h] + adh;
    v = (v > 0.f) ? v : 0.2f * v;
    den += __expf(v);
  }
  den += __shfl_xor(den, 8);
  den += __shfl_xor(den, 16);
  den += __shfl_xor(den, 32);
  const float inv = 1.f / (den + 1e-16f);
  const int f4 = lane & (F4 - 1);
  const int hbase = (lane / F4) * HPG;
  float4 acc0 = make_float4(0.f, 0.f, 0.f, 0.f);
  float4 acc1 = make_float4(0.f, 0.f, 0.f, 0.f);
  float4 acc2 = make_float4(0.f, 0.f, 0.f, 0.f);
  float4 acc3 = make_float4(0.f, 0.f, 0.f, 0.f);
  for (int c0 = 0; c0 < deg; c0 += 8) {
    float aval = 0.f;
    int sj = 0;
    if (c0 + j < deg) {
      sj = col[start + c0 + j];
      float v = a_s[(size_t)sj * 8 + h] + adh;
      v = (v > 0.f) ? v : 0.2f * v;
      aval = __expf(v) * inv;
    }
    s_alpha[wid][j][h] = aval;
    if (h == 0) s_cols[wid][j] = sj;
    __builtin_amdgcn_wave_barrier();
    const int ce = min(8, deg - c0);
    for (int e = 0; e < ce; ++e) {
      int s = s_cols[wid][e];
      float4 fv = *reinterpret_cast<const float4*>(feat + (size_t)s * F + f4 * 4);
      if constexpr (HPG == 4) {
        float4 al = *reinterpret_cast<const float4*>(&s_alpha[wid][e][hbase]);
        acc0.x = fmaf(al.x, fv.x, acc0.x); acc0.y = fmaf(al.x, fv.y, acc0.y);
        acc0.z = fmaf(al.x, fv.z, acc0.z); acc0.w = fmaf(al.x, fv.w, acc0.w);
        acc1.x = fmaf(al.y, fv.x, acc1.x); acc1.y = fmaf(al.y, fv.y, acc1.y);
        acc1.z = fmaf(al.y, fv.z, acc1.z); acc1.w = fmaf(al.y, fv.w, acc1.w);
        acc2.x = fmaf(al.z, fv.x, acc2.x); acc2.y = fmaf(al.z, fv.y, acc2.y);
        acc2.z = fmaf(al.z, fv.z, acc2.z); acc2.w = fmaf(al.z, fv.w, acc2.w);
        acc3.x = fmaf(al.w, fv.x, acc3.x); acc3.y = fmaf(al.w, fv.y, acc3.y);
        acc3.z = fmaf(al.w, fv.z, acc3.z); acc3.w = fmaf(al.w, fv.w, acc3.w);
      } else {
        float2 al = *reinterpret_cast<const float2*>(&s_alpha[wid][e][hbase]);
        acc0.x = fmaf(al.x, fv.x, acc0.x); acc0.y = fmaf(al.x, fv.y, acc0.y);
        acc0.z = fmaf(al.x, fv.z, acc0.z); acc0.w = fmaf(al.x, fv.w, acc0.w);
        acc1.x = fmaf(al.y, fv.x, acc1.x); acc1.y = fmaf(al.y, fv.y, acc1.y);
        acc1.z = fmaf(al.y, fv.z, acc1.z); acc1.w = fmaf(al.y, fv.w, acc1.w);
      }
    }
    __builtin_amdgcn_wave_barrier();
  }
  float* outp = agg + (size_t)node * 8 * F + (size_t)hbase * F + f4 * 4;
  *reinterpret_cast<float4*>(outp) = acc0;
  *reinterpret_cast<float4*>(outp + F) = acc1;
  if constexpr (HPG == 4) {
    *reinterpret_cast<float4*>(outp + 2 * F) = acc2;
    *reinterpret_cast<float4*>(outp + 3 * F) = acc3;
  }
}

// ==================== LSTM weight prep ====================
// Only i,g,o gates needed (f gate multiplies c0=0). Packed 192 columns:
// jp<64 -> i (j=jp), 64..127 -> g (j=jp+64), 128..191 -> o (j=jp+64).

__global__ void prep_lstm_kernel(const float* __restrict__ W_ih, const float* __restrict__ b_ih,
                                 const float* __restrict__ b_hh, float* __restrict__ Wt,
                                 float* __restrict__ bsum) {
  int idx = blockIdx.x * 256 + threadIdx.x;
  if (idx < 512 * 192) {
    int k = idx / 192, jp = idx - k * 192;
    int j = (jp < 64) ? jp : jp + 64;
    Wt[idx] = W_ih[(size_t)j * 512 + k];
  }
  if (idx < 192) {
    int j = (idx < 64) ? idx : idx + 64;
    bsum[idx] = b_ih[j] + b_hh[j];
  }
}

// ==================== fused LSTM activation + attcoef2 ====================
// 4 nodes per 256-thread block (grid ~5000): thread (nl,j) computes h2[node,j]
// in registers, stages it in LDS, then 16 threads/node compute the attention
// coefficients. Keeps grid large (R5 lesson) while dropping one launch.

__global__ __launch_bounds__(256) void lstm_act_attcoef_kernel(
    const float* __restrict__ gates, const float* __restrict__ watt2,
    float* __restrict__ h2, float* __restrict__ a_s2, float* __restrict__ a_d2,
    int n) {
  __shared__ float h2t[4][64];
  __shared__ float wbuf[64 * 16];
  const int tid = threadIdx.x;
  reinterpret_cast<float4*>(wbuf)[tid] = reinterpret_cast<const float4*>(watt2)[tid];
  const int nl = tid >> 6, j = tid & 63;
  const int node = blockIdx.x * 4 + nl;
  float hv = 0.f;
  if (node < n) {
    const float* g = gates + (size_t)node * 192;
    float iv = g[j], gv = g[64 + j], ov = g[128 + j];
    float c = (1.f / (1.f + __expf(-iv))) * tanhf(gv);
    hv = fmaxf((1.f / (1.f + __expf(-ov))) * tanhf(c), 0.f);
    h2[(size_t)node * 64 + j] = hv;
  }
  h2t[nl][j] = hv;
  __syncthreads();
  if (j < 16 && node < n) {
    float s = 0.f;
#pragma unroll 16
    for (int f = 0; f < 64; ++f) s = fmaf(h2t[nl][f], wbuf[f * 16 + j], s);
    if (j < 8) a_s2[(size_t)node * 8 + j] = s;
    else       a_d2[(size_t)node * 8 + (j - 8)] = s;
  }
}

// ==================== final row softmax (512 wide) ====================

__global__ __launch_bounds__(256) void softmax512_kernel(const float* __restrict__ in,
                                                         float* __restrict__ out) {
  const int node = blockIdx.x;
  const int tid = threadIdx.x;
  __shared__ float red[256];
  float v0 = in[(size_t)node * 512 + tid];
  float v1 = in[(size_t)node * 512 + 256 + tid];
  red[tid] = fmaxf(v0, v1);
  __syncthreads();
  for (int s = 128; s >= 1; s >>= 1) {
    if (tid < s) red[tid] = fmaxf(red[tid], red[tid + s]);
    __syncthreads();
  }
  float mm = red[0];
  __syncthreads();
  float e0 = expf(v0 - mm), e1 = expf(v1 - mm);
  red[tid] = e0 + e1;
  __syncthreads();
  for (int s = 128; s >= 1; s >>= 1) {
    if (tid < s) red[tid] += red[tid + s];
    __syncthreads();
  }
  float inv = 1.f / red[0];
  out[(size_t)node * 512 + tid] = e0 * inv;
  out[(size_t)node * 512 + 256 + tid] = e1 * inv;
}

// ============================ launch ============================

extern "C" void kernel_launch(void* const* d_in, const int* in_sizes, int n_in,
                              void* d_out, int out_size, void* d_ws, size_t ws_size,
                              hipStream_t stream) {
  const float* x      = (const float*)d_in[0];
  const int*   ei     = (const int*)d_in[1];
  const float* W1     = (const float*)d_in[3];
  const float* att_s1 = (const float*)d_in[4];
  const float* att_d1 = (const float*)d_in[5];
  const float* bias1  = (const float*)d_in[6];
  const float* W_ih   = (const float*)d_in[7];
  const float* b_ih   = (const float*)d_in[9];
  const float* b_hh   = (const float*)d_in[10];
  const float* W2     = (const float*)d_in[11];
  const float* att_s2 = (const float*)d_in[12];
  const float* att_d2 = (const float*)d_in[13];
  const float* bias2  = (const float*)d_in[14];
  float* out = (float*)d_out;

  const int N = in_sizes[0] / 128;
  const int E = in_sizes[1] / 2;
  const int* src = ei;
  const int* dst = ei + E;

  char* p = (char*)d_ws;
  auto alloc = [&](size_t bytes) {
    char* r = p;
    p += (bytes + 255) & ~(size_t)255;
    return r;
  };
  float* slotA = (float*)alloc((size_t)N * 1024 * 4);  // agg1; later gates+h2+agg2
  float* slotB = (float*)alloc((size_t)N * 512 * 4);   // g1; later h3p
  float* a_s1 = (float*)alloc((size_t)N * 8 * 4);
  float* a_d1 = (float*)alloc((size_t)N * 8 * 4);
  float* a_s2 = (float*)alloc((size_t)N * 8 * 4);
  float* a_d2 = (float*)alloc((size_t)N * 8 * 4);
  float* watt1 = (float*)alloc(128 * 16 * 4);
  float* watt2 = (float*)alloc(64 * 16 * 4);
  float* Wt   = (float*)alloc((size_t)512 * 192 * 4);
  float* bsum = (float*)alloc(192 * 4);
  int* deg    = (int*)alloc((size_t)2 * N * 4);  // deg + wp adjacent (one memset)
  int* wp     = deg + N;
  int* rowptr = (int*)alloc((size_t)(N + 1) * 4);
  int* col    = (int*)alloc((size_t)(E + N) * 4);

  float* agg1  = slotA;                    // [N,8,128], dead after proj1
  float* g1    = slotB;                    // [N,512], dead after LSTM gemm
  float* gates = slotA;                    // [N,192]
  float* h2    = slotA + (size_t)N * 192;  // [N,64]
  float* agg2  = slotA + (size_t)N * 320;  // [N,8,64] (320+512=832 <= 1024)
  float* h3p   = slotB;                    // [N,512] logits

  // ---- CSR build ----
  hipMemsetAsync(deg, 0, (size_t)2 * N * 4, stream);
  count_kernel<<<(E + 255) / 256, 256, 0, stream>>>(dst, deg, E);
  scan_kernel<<<1, 1024, 0, stream>>>(deg, rowptr, N);
  scatter_kernel<<<(E + N + 255) / 256, 256, 0, stream>>>(src, dst, rowptr, wp, col, E, N);

  // ---- weight prep ----
  prep_watt_kernel<<<(128 * 16 + 255) / 256, 256, 0, stream>>>(W1, att_s1, att_d1, watt1, 128);
  prep_watt_kernel<<<(64 * 16 + 255) / 256, 256, 0, stream>>>(W2, att_s2, att_d2, watt2, 64);
  prep_lstm_kernel<<<(512 * 192 + 255) / 256, 256, 0, stream>>>(W_ih, b_ih, b_hh, Wt, bsum);

  // ---- GATConv1: coeffs on x, aggregate x, project ----
  attcoef_kernel<128><<<(N + 15) / 16, 256, 0, stream>>>(x, watt1, a_s1, a_d1, N);
  gat_aggregate_wave<128><<<(N + 3) / 4, 256, 0, stream>>>(x, a_s1, a_d1, rowptr, col, agg1, N);
  {
    dim3 g(1, (N + 127) / 128, 8);
    gemm_kernel<128><<<g, 256, 0, stream>>>(agg1, W1, g1, bias1,
                                            N, 128, 1024, 512, 512, 128, 64, 64, 64);
  }

  // ---- LSTM (single step, h0=c0=0): GEMM + fused act/attcoef2 ----
  {
    dim3 g(3, (N + 63) / 64, 1);
    gemm_kernel<64><<<g, 256, 0, stream>>>(g1, Wt, gates, bsum,
                                           N, 512, 512, 192, 192, 0, 0, 0, 0);
  }
  lstm_act_attcoef_kernel<<<(N + 3) / 4, 256, 0, stream>>>(gates, watt2, h2, a_s2, a_d2, N);

  // ---- GATConv2: aggregate h2, project, row softmax ----
  gat_aggregate_wave<64><<<(N + 3) / 4, 256, 0, stream>>>(h2, a_s2, a_d2, rowptr, col, agg2, N);
  {
    dim3 g(1, (N + 127) / 128, 8);
    gemm_kernel<128><<<g, 256, 0, stream>>>(agg2, W2, h3p, bias2,
                                            N, 64, 512, 512, 512, 64, 64, 64, 64);
  }
  softmax512_kernel<<<N, 256, 0, stream>>>(h3p, out);
}

// Round 7
// 388.382 us; speedup vs baseline: 1.2115x; 1.0677x over previous
//
#include <hip/hip_runtime.h>
#include <math.h>

// ============================ CSR build ============================

__global__ void count_kernel(const int* __restrict__ dst, int* __restrict__ deg, int E) {
  int i = blockIdx.x * 256 + threadIdx.x;
  if (i < E) atomicAdd(&deg[dst[i]], 1);
}

// exclusive scan of (deg[i]+1) (+1 = self loop); single block, 8 vals/thread
__global__ void scan_kernel(const int* __restrict__ deg, int* __restrict__ rowptr, int n) {
  __shared__ int buf[1024];
  __shared__ int carry;
  if (threadIdx.x == 0) carry = 0;
  __syncthreads();
  for (int base = 0; base < n; base += 8192) {
    int v[8];
    int tsum = 0;
    int i0 = base + (int)threadIdx.x * 8;
#pragma unroll
    for (int k = 0; k < 8; ++k) {
      int i = i0 + k;
      v[k] = (i < n) ? (deg[i] + 1) : 0;
      tsum += v[k];
    }
    int incl = tsum;
    buf[threadIdx.x] = incl;
    __syncthreads();
    for (int s = 1; s < 1024; s <<= 1) {
      int t = (threadIdx.x >= (unsigned)s) ? buf[threadIdx.x - s] : 0;
      __syncthreads();
      incl += t;
      buf[threadIdx.x] = incl;
      __syncthreads();
    }
    int excl = carry + incl - tsum;
#pragma unroll
    for (int k = 0; k < 8; ++k) {
      int i = i0 + k;
      if (i < n) rowptr[i] = excl;
      excl += v[k];
    }
    int total = buf[1023];
    __syncthreads();
    if (threadIdx.x == 0) carry += total;
    __syncthreads();
  }
  if (threadIdx.x == 0) rowptr[n] = carry;
}

__global__ void scatter_kernel(const int* __restrict__ src, const int* __restrict__ dst,
                               const int* __restrict__ rowptr, int* __restrict__ wp,
                               int* __restrict__ col, int E, int n) {
  int i = blockIdx.x * 256 + threadIdx.x;
  if (i < E) {
    int d = dst[i];
    int p = rowptr[d] + atomicAdd(&wp[d], 1);
    col[p] = src[i];
  } else if (i < E + n) {
    int d = i - E;
    int p = rowptr[d] + atomicAdd(&wp[d], 1);
    col[p] = d;
  }
}

// ============================ fp32 GEMM (register-prefetch) ============================
// C[M,*] = A[M,K] @ B[K,*] (+bias). blockIdx.z adds aZ/bZ/cZ/biasZ element
// offsets; used both for per-head batched projections AND split-K (aZ=K/2,
// bZ=(K/2)*ldb, cZ=M*ldc gives two partial-sum buffers). BN=64, BK=16,
// 256 threads, per-thread (BMt/16)x4 accumulator.

template <int BMt>
__global__ __launch_bounds__(256) void gemm_kernel(
    const float* __restrict__ A, const float* __restrict__ B,
    float* __restrict__ C, const float* __restrict__ bias,
    int M, int K, int lda, int ldb, int ldc,
    int aZ, int bZ, int cZ, int biasZ) {
  constexpr int BNt = 64, BKt = 16;
  constexpr int TM = BMt / 16;
  constexpr int AST = (BMt * BKt) / (256 * 4);
  __shared__ float As[BKt][BMt + 4];
  __shared__ float Bs[BKt][BNt];
  const int z = blockIdx.z;
  A += (size_t)z * aZ;
  B += (size_t)z * bZ;
  C += (size_t)z * cZ;
  const int tid = threadIdx.x;
  const int bm = blockIdx.y * BMt;
  const int bn = blockIdx.x * BNt;
  const int tm = (tid >> 4) * TM;
  const int tn = (tid & 15) * 4;
  int arow_[AST], akq_[AST];
#pragma unroll
  for (int i = 0; i < AST; ++i) {
    int idx = tid + i * 256;
    arow_[i] = idx >> 2;
    akq_[i] = (idx & 3) * 4;
  }
  const int bk = tid >> 4, bn4 = (tid & 15) * 4;
  float4 pa[AST], pb;
#pragma unroll
  for (int i = 0; i < AST; ++i) {
    pa[i] = make_float4(0.f, 0.f, 0.f, 0.f);
    if (bm + arow_[i] < M)
      pa[i] = *reinterpret_cast<const float4*>(A + (size_t)(bm + arow_[i]) * lda + akq_[i]);
  }
  pb = *reinterpret_cast<const float4*>(B + (size_t)bk * ldb + bn + bn4);
  float acc[TM][4] = {};
  for (int k0 = 0; k0 < K; k0 += BKt) {
#pragma unroll
    for (int i = 0; i < AST; ++i) {
      As[akq_[i] + 0][arow_[i]] = pa[i].x; As[akq_[i] + 1][arow_[i]] = pa[i].y;
      As[akq_[i] + 2][arow_[i]] = pa[i].z; As[akq_[i] + 3][arow_[i]] = pa[i].w;
    }
    *reinterpret_cast<float4*>(&Bs[bk][bn4]) = pb;
    __syncthreads();
    const int kn = k0 + BKt;
    if (kn < K) {
#pragma unroll
      for (int i = 0; i < AST; ++i) {
        float4 t = make_float4(0.f, 0.f, 0.f, 0.f);
        if (bm + arow_[i] < M)
          t = *reinterpret_cast<const float4*>(A + (size_t)(bm + arow_[i]) * lda + kn + akq_[i]);
        pa[i] = t;
      }
      pb = *reinterpret_cast<const float4*>(B + (size_t)(kn + bk) * ldb + bn + bn4);
    }
#pragma unroll
    for (int k = 0; k < BKt; ++k) {
      float a[TM], b[4];
#pragma unroll
      for (int i = 0; i < TM; ++i) a[i] = As[k][tm + i];
#pragma unroll
      for (int j = 0; j < 4; ++j) b[j] = Bs[k][tn + j];
#pragma unroll
      for (int i = 0; i < TM; ++i)
#pragma unroll
        for (int j = 0; j < 4; ++j) acc[i][j] = fmaf(a[i], b[j], acc[i][j]);
    }
    __syncthreads();
  }
  float4 bz = make_float4(0.f, 0.f, 0.f, 0.f);
  if (bias) bz = *reinterpret_cast<const float4*>(bias + (size_t)z * biasZ + bn + tn);
#pragma unroll
  for (int i = 0; i < TM; ++i) {
    int m = bm + tm + i;
    if (m < M) {
      float4 o;
      o.x = acc[i][0] + bz.x; o.y = acc[i][1] + bz.y;
      o.z = acc[i][2] + bz.z; o.w = acc[i][3] + bz.w;
      *reinterpret_cast<float4*>(C + (size_t)m * ldc + bn + tn) = o;
    }
  }
}

// ==================== merged weight prep (one launch) ====================
// [0, 98304): Wt (LSTM packed i,g,o transpose)   [98304, 98496): bsum
// [98496, 100544): watt1 (F=128)                 [100544, 101568): watt2 (F=64)

__global__ void prep_all_kernel(const float* __restrict__ W_ih, const float* __restrict__ b_ih,
                                const float* __restrict__ b_hh, const float* __restrict__ W1,
                                const float* __restrict__ as1, const float* __restrict__ ad1,
                                const float* __restrict__ W2, const float* __restrict__ as2,
                                const float* __restrict__ ad2, float* __restrict__ Wt,
                                float* __restrict__ bsum, float* __restrict__ watt1,
                                float* __restrict__ watt2) {
  int idx = blockIdx.x * 256 + threadIdx.x;
  if (idx < 98304) {
    int k = idx / 192, jp = idx - k * 192;
    int j = (jp < 64) ? jp : jp + 64;
    Wt[idx] = W_ih[(size_t)j * 512 + k];
  } else if (idx < 98496) {
    int jp = idx - 98304;
    int j = (jp < 64) ? jp : jp + 64;
    bsum[jp] = b_ih[j] + b_hh[j];
  } else if (idx < 100544) {
    int t = idx - 98496;
    int f = t >> 4, c = t & 15;
    int k = c & 7;
    const float* att = ((c < 8) ? as1 : ad1) + k * 64;
    const float* w = W1 + (size_t)f * 512 + k * 64;
    float s = 0.f;
#pragma unroll
    for (int j = 0; j < 64; ++j) s = fmaf(w[j], att[j], s);
    watt1[t] = s;
  } else if (idx < 101568) {
    int t = idx - 100544;
    int f = t >> 4, c = t & 15;
    int k = c & 7;
    const float* att = ((c < 8) ? as2 : ad2) + k * 64;
    const float* w = W2 + (size_t)f * 512 + k * 64;
    float s = 0.f;
#pragma unroll
    for (int j = 0; j < 64; ++j) s = fmaf(w[j], att[j], s);
    watt2[t] = s;
  }
}

// ==================== attention coefficients (layer 1) ====================

template <int F>
__global__ __launch_bounds__(256) void attcoef_kernel(
    const float* __restrict__ feat, const float* __restrict__ watt,
    float* __restrict__ a_s, float* __restrict__ a_d, int n) {
  __shared__ float rows[16 * F];
  __shared__ float wbuf[F * 16];
  const int n0 = blockIdx.x * 16;
  const int tid = threadIdx.x;
  if (n0 + 16 <= n) {
    const float4* g = reinterpret_cast<const float4*>(feat + (size_t)n0 * F);
    float4* l = reinterpret_cast<float4*>(rows);
    for (int i = tid; i < 16 * F / 4; i += 256) l[i] = g[i];
  } else {
    for (int i = tid; i < 16 * F; i += 256) {
      int r = i / F;
      rows[i] = (n0 + r < n) ? feat[(size_t)(n0 + r) * F + (i - r * F)] : 0.f;
    }
  }
  {
    const float4* g = reinterpret_cast<const float4*>(watt);
    float4* l = reinterpret_cast<float4*>(wbuf);
    for (int i = tid; i < F * 16 / 4; i += 256) l[i] = g[i];
  }
  __syncthreads();
  const int local = tid >> 4, c = tid & 15;
  float s = 0.f;
#pragma unroll 8
  for (int f = 0; f < F; ++f) s = fmaf(rows[local * F + f], wbuf[f * 16 + c], s);
  const int node = n0 + local;
  if (node < n) {
    if (c < 8) a_s[(size_t)node * 8 + c] = s;
    else       a_d[(size_t)node * 8 + (c - 8)] = s;
  }
}

// ==================== GAT pre-aggregation: one WAVE per dst node ====================
// 4 independent waves/block, no __syncthreads. Heads split across lane GROUPS;
// explicit float4 accumulators (no indexed local arrays -> no scratch spill).
// Alpha + col staged in per-wave LDS chunks of 8 edges (DS ops wave-ordered).
// No max-subtraction: |a_s+a_d| <~ 8 so exp is safe.

template <int F>
__global__ __launch_bounds__(256) void gat_aggregate_wave(
    const float* __restrict__ feat, const float* __restrict__ a_s,
    const float* __restrict__ a_d, const int* __restrict__ rowptr,
    const int* __restrict__ col, float* __restrict__ agg, int n) {
  constexpr int F4 = F / 4;
  constexpr int HPG = (F == 128) ? 4 : 2;
  __shared__ float s_alpha[4][8][8];
  __shared__ int s_cols[4][8];
  const int wid = threadIdx.x >> 6;
  const int lane = threadIdx.x & 63;
  const int node = blockIdx.x * 4 + wid;
  if (node >= n) return;
  const int start = rowptr[node];
  const int deg = rowptr[node + 1] - start;
  const int j = lane >> 3;
  const int h = lane & 7;
  const float adh = a_d[(size_t)node * 8 + h];
  float den = 0.f;
  for (int e = j; e < deg; e += 8) {
    int s = col[start + e];
    float v = a_s[(size_t)s * 8 + h] + adh;
    v = (v > 0.f) ? v : 0.2f * v;
    den += __expf(v);
  }
  den += __shfl_xor(den, 8);
  den += __shfl_xor(den, 16);
  den += __shfl_xor(den, 32);
  const float inv = 1.f / (den + 1e-16f);
  const int f4 = lane & (F4 - 1);
  const int hbase = (lane / F4) * HPG;
  float4 acc0 = make_float4(0.f, 0.f, 0.f, 0.f);
  float4 acc1 = make_float4(0.f, 0.f, 0.f, 0.f);
  float4 acc2 = make_float4(0.f, 0.f, 0.f, 0.f);
  float4 acc3 = make_float4(0.f, 0.f, 0.f, 0.f);
  for (int c0 = 0; c0 < deg; c0 += 8) {
    float aval = 0.f;
    int sj = 0;
    if (c0 + j < deg) {
      sj = col[start + c0 + j];
      float v = a_s[(size_t)sj * 8 + h] + adh;
      v = (v > 0.f) ? v : 0.2f * v;
      aval = __expf(v) * inv;
    }
    s_alpha[wid][j][h] = aval;
    if (h == 0) s_cols[wid][j] = sj;
    __builtin_amdgcn_wave_barrier();
    const int ce = min(8, deg - c0);
    for (int e = 0; e < ce; ++e) {
      int s = s_cols[wid][e];
      float4 fv = *reinterpret_cast<const float4*>(feat + (size_t)s * F + f4 * 4);
      if constexpr (HPG == 4) {
        float4 al = *reinterpret_cast<const float4*>(&s_alpha[wid][e][hbase]);
        acc0.x = fmaf(al.x, fv.x, acc0.x); acc0.y = fmaf(al.x, fv.y, acc0.y);
        acc0.z = fmaf(al.x, fv.z, acc0.z); acc0.w = fmaf(al.x, fv.w, acc0.w);
        acc1.x = fmaf(al.y, fv.x, acc1.x); acc1.y = fmaf(al.y, fv.y, acc1.y);
        acc1.z = fmaf(al.y, fv.z, acc1.z); acc1.w = fmaf(al.y, fv.w, acc1.w);
        acc2.x = fmaf(al.z, fv.x, acc2.x); acc2.y = fmaf(al.z, fv.y, acc2.y);
        acc2.z = fmaf(al.z, fv.z, acc2.z); acc2.w = fmaf(al.z, fv.w, acc2.w);
        acc3.x = fmaf(al.w, fv.x, acc3.x); acc3.y = fmaf(al.w, fv.y, acc3.y);
        acc3.z = fmaf(al.w, fv.z, acc3.z); acc3.w = fmaf(al.w, fv.w, acc3.w);
      } else {
        float2 al = *reinterpret_cast<const float2*>(&s_alpha[wid][e][hbase]);
        acc0.x = fmaf(al.x, fv.x, acc0.x); acc0.y = fmaf(al.x, fv.y, acc0.y);
        acc0.z = fmaf(al.x, fv.z, acc0.z); acc0.w = fmaf(al.x, fv.w, acc0.w);
        acc1.x = fmaf(al.y, fv.x, acc1.x); acc1.y = fmaf(al.y, fv.y, acc1.y);
        acc1.z = fmaf(al.y, fv.z, acc1.z); acc1.w = fmaf(al.y, fv.w, acc1.w);
      }
    }
    __builtin_amdgcn_wave_barrier();
  }
  float* outp = agg + (size_t)node * 8 * F + (size_t)hbase * F + f4 * 4;
  *reinterpret_cast<float4*>(outp) = acc0;
  *reinterpret_cast<float4*>(outp + F) = acc1;
  if constexpr (HPG == 4) {
    *reinterpret_cast<float4*>(outp + 2 * F) = acc2;
    *reinterpret_cast<float4*>(outp + 3 * F) = acc3;
  }
}

// ==================== fused LSTM split-K reduce + activation + attcoef2 ====================
// gates arrive as 2 partial buffers (split-K halves); this kernel adds them
// + bsum, applies the LSTM nonlinearity + relu, writes h2, and computes the
// layer-2 attention coefficients. 4 nodes per block (grid ~5000).

__global__ __launch_bounds__(256) void lstm_act_attcoef_kernel(
    const float* __restrict__ gp0, const float* __restrict__ bsum,
    const float* __restrict__ watt2, float* __restrict__ h2,
    float* __restrict__ a_s2, float* __restrict__ a_d2, int n) {
  __shared__ float h2t[4][64];
  __shared__ float wbuf[64 * 16];
  const int tid = threadIdx.x;
  reinterpret_cast<float4*>(wbuf)[tid] = reinterpret_cast<const float4*>(watt2)[tid];
  const int nl = tid >> 6, j = tid & 63;
  const int node = blockIdx.x * 4 + nl;
  const float* gp1 = gp0 + (size_t)n * 192;
  float hv = 0.f;
  if (node < n) {
    const float* g0 = gp0 + (size_t)node * 192;
    const float* g1 = gp1 + (size_t)node * 192;
    float iv = g0[j] + g1[j] + bsum[j];
    float gv = g0[64 + j] + g1[64 + j] + bsum[64 + j];
    float ov = g0[128 + j] + g1[128 + j] + bsum[128 + j];
    float c = (1.f / (1.f + __expf(-iv))) * tanhf(gv);
    hv = fmaxf((1.f / (1.f + __expf(-ov))) * tanhf(c), 0.f);
    h2[(size_t)node * 64 + j] = hv;
  }
  h2t[nl][j] = hv;
  __syncthreads();
  if (j < 16 && node < n) {
    float s = 0.f;
#pragma unroll 16
    for (int f = 0; f < 64; ++f) s = fmaf(h2t[nl][f], wbuf[f * 16 + j], s);
    if (j < 8) a_s2[(size_t)node * 8 + j] = s;
    else       a_d2[(size_t)node * 8 + (j - 8)] = s;
  }
}

// ==================== final row softmax: one WAVE per node ====================
// 4 waves/block, register-resident 8 floats/lane, shuffle reductions only.

__global__ __launch_bounds__(256) void softmax512_wave(const float* __restrict__ in,
                                                       float* __restrict__ out, int n) {
  const int wid = threadIdx.x >> 6, lane = threadIdx.x & 63;
  const int node = blockIdx.x * 4 + wid;
  if (node >= n) return;
  const float4* ip = reinterpret_cast<const float4*>(in + (size_t)node * 512);
  float4 v0 = ip[lane];
  float4 v1 = ip[64 + lane];
  float m = fmaxf(fmaxf(fmaxf(v0.x, v0.y), fmaxf(v0.z, v0.w)),
                  fmaxf(fmaxf(v1.x, v1.y), fmaxf(v1.z, v1.w)));
#pragma unroll
  for (int d = 1; d < 64; d <<= 1) m = fmaxf(m, __shfl_xor(m, d));
  float4 e0, e1;
  e0.x = __expf(v0.x - m); e0.y = __expf(v0.y - m);
  e0.z = __expf(v0.z - m); e0.w = __expf(v0.w - m);
  e1.x = __expf(v1.x - m); e1.y = __expf(v1.y - m);
  e1.z = __expf(v1.z - m); e1.w = __expf(v1.w - m);
  float s = e0.x + e0.y + e0.z + e0.w + e1.x + e1.y + e1.z + e1.w;
#pragma unroll
  for (int d = 1; d < 64; d <<= 1) s += __shfl_xor(s, d);
  float inv = 1.f / s;
  e0.x *= inv; e0.y *= inv; e0.z *= inv; e0.w *= inv;
  e1.x *= inv; e1.y *= inv; e1.z *= inv; e1.w *= inv;
  float4* op = reinterpret_cast<float4*>(out + (size_t)node * 512);
  op[lane] = e0;
  op[64 + lane] = e1;
}

// ============================ launch ============================

extern "C" void kernel_launch(void* const* d_in, const int* in_sizes, int n_in,
                              void* d_out, int out_size, void* d_ws, size_t ws_size,
                              hipStream_t stream) {
  const float* x      = (const float*)d_in[0];
  const int*   ei     = (const int*)d_in[1];
  const float* W1     = (const float*)d_in[3];
  const float* att_s1 = (const float*)d_in[4];
  const float* att_d1 = (const float*)d_in[5];
  const float* bias1  = (const float*)d_in[6];
  const float* W_ih   = (const float*)d_in[7];
  const float* b_ih   = (const float*)d_in[9];
  const float* b_hh   = (const float*)d_in[10];
  const float* W2     = (const float*)d_in[11];
  const float* att_s2 = (const float*)d_in[12];
  const float* att_d2 = (const float*)d_in[13];
  const float* bias2  = (const float*)d_in[14];
  float* out = (float*)d_out;

  const int N = in_sizes[0] / 128;
  const int E = in_sizes[1] / 2;
  const int* src = ei;
  const int* dst = ei + E;

  char* p = (char*)d_ws;
  auto alloc = [&](size_t bytes) {
    char* r = p;
    p += (bytes + 255) & ~(size_t)255;
    return r;
  };
  float* slotA = (float*)alloc((size_t)N * 1024 * 4);  // agg1; later gates2+h2+agg2
  float* slotB = (float*)alloc((size_t)N * 512 * 4);   // g1; later h3p
  float* a_s1 = (float*)alloc((size_t)N * 8 * 4);
  float* a_d1 = (float*)alloc((size_t)N * 8 * 4);
  float* a_s2 = (float*)alloc((size_t)N * 8 * 4);
  float* a_d2 = (float*)alloc((size_t)N * 8 * 4);
  float* watt1 = (float*)alloc(128 * 16 * 4);
  float* watt2 = (float*)alloc(64 * 16 * 4);
  float* Wt   = (float*)alloc((size_t)512 * 192 * 4);
  float* bsum = (float*)alloc(192 * 4);
  int* deg    = (int*)alloc((size_t)2 * N * 4);  // deg + wp adjacent (one memset)
  int* wp     = deg + N;
  int* rowptr = (int*)alloc((size_t)(N + 1) * 4);
  int* col    = (int*)alloc((size_t)(E + N) * 4);

  float* agg1   = slotA;                    // [N,8,128], dead after proj1
  float* g1     = slotB;                    // [N,512], dead after LSTM gemm
  float* gates2 = slotA;                    // 2x[N,192] split-K partials
  float* h2     = slotA + (size_t)N * 384;  // [N,64]
  float* agg2   = slotA + (size_t)N * 448;  // [N,8,64] (448+512=960 <= 1024)
  float* h3p    = slotB;                    // [N,512] logits

  // ---- CSR build ----
  hipMemsetAsync(deg, 0, (size_t)2 * N * 4, stream);
  count_kernel<<<(E + 255) / 256, 256, 0, stream>>>(dst, deg, E);
  scan_kernel<<<1, 1024, 0, stream>>>(deg, rowptr, N);
  scatter_kernel<<<(E + N + 255) / 256, 256, 0, stream>>>(src, dst, rowptr, wp, col, E, N);

  // ---- merged weight prep ----
  prep_all_kernel<<<(101568 + 255) / 256, 256, 0, stream>>>(
      W_ih, b_ih, b_hh, W1, att_s1, att_d1, W2, att_s2, att_d2,
      Wt, bsum, watt1, watt2);

  // ---- GATConv1: coeffs on x, aggregate x, project ----
  attcoef_kernel<128><<<(N + 15) / 16, 256, 0, stream>>>(x, watt1, a_s1, a_d1, N);
  gat_aggregate_wave<128><<<(N + 3) / 4, 256, 0, stream>>>(x, a_s1, a_d1, rowptr, col, agg1, N);
  {
    dim3 g(1, (N + 127) / 128, 8);
    gemm_kernel<128><<<g, 256, 0, stream>>>(agg1, W1, g1, bias1,
                                            N, 128, 1024, 512, 512, 128, 64, 64, 64);
  }

  // ---- LSTM: split-K=2 GEMM (partials) + fused reduce/act/attcoef2 ----
  {
    dim3 g(3, (N + 63) / 64, 2);
    gemm_kernel<64><<<g, 256, 0, stream>>>(g1, Wt, gates2, nullptr,
                                           N, 256, 512, 192, 192,
                                           256, 256 * 192, N * 192, 0);
  }
  lstm_act_attcoef_kernel<<<(N + 3) / 4, 256, 0, stream>>>(gates2, bsum, watt2,
                                                           h2, a_s2, a_d2, N);

  // ---- GATConv2: aggregate h2, project, row softmax ----
  gat_aggregate_wave<64><<<(N + 3) / 4, 256, 0, stream>>>(h2, a_s2, a_d2, rowptr, col, agg2, N);
  {
    dim3 g(1, (N + 127) / 128, 8);
    gemm_kernel<128><<<g, 256, 0, stream>>>(agg2, W2, h3p, bias2,
                                            N, 64, 512, 512, 512, 64, 64, 64, 64);
  }
  softmax512_wave<<<(N + 3) / 4, 256, 0, stream>>>(h3p, out, N);
}